// Round 1
// baseline (555.693 us; speedup 1.0000x reference)
//
#include <hip/hip_runtime.h>
#include <math.h>

#define NN 100000
#define NE 1600000
#define FIN 64
#define HID 16
#define NC 40

__global__ void k_deg(const int* __restrict__ dst, const float* __restrict__ ew,
                      float* __restrict__ deg) {
    int e = blockIdx.x * blockDim.x + threadIdx.x;
    if (e < NE) atomicAdd(&deg[dst[e]], ew[e]);
}

__global__ void k_dinv(float* deg) {
    int i = blockIdx.x * blockDim.x + threadIdx.x;
    if (i < NN) {
        float d = deg[i];
        deg[i] = d > 0.f ? rsqrtf(fmaxf(d, 1e-30f)) : 0.f;
    }
}

__global__ void k_norm(const int* __restrict__ src, const int* __restrict__ dst,
                       const float* __restrict__ ew, const float* __restrict__ dinv,
                       float* __restrict__ norm) {
    int e = blockIdx.x * blockDim.x + threadIdx.x;
    if (e < NE) norm[e] = -dinv[src[e]] * ew[e] * dinv[dst[e]];
}

// A1[n][j] = sum_f x[n][f] * W1[0][f][j];  B0[n][j] = sum_f x[n][f] * W1[1][f][j]
__global__ void k_mm1(const float* __restrict__ x, const float* __restrict__ W1,
                      float* __restrict__ A1, float* __restrict__ B0) {
    __shared__ float w[2 * FIN * HID];  // 2048 floats = 8 KB
    int tid = threadIdx.x;
    for (int i = tid; i < 2 * FIN * HID; i += 256) w[i] = W1[i];
    __syncthreads();
    int node = blockIdx.x * 8 + (tid >> 5);
    int c = tid & 31;
    int sel = c >> 4, jj = c & 15;
    if (node >= NN) return;
    const float* xr = x + node * FIN;
    const float* wp = w + sel * (FIN * HID) + jj;
    float acc = 0.f;
    #pragma unroll
    for (int f = 0; f < FIN; ++f) acc += xr[f] * wp[f * HID];
    if (sel == 0) A1[node * HID + jj] = acc;
    else          B0[node * HID + jj] = acc;
}

// acc1[dst[e]][f] += norm[e] * B0[src[e]][f],  16 consecutive threads per edge
__global__ void k_scatter16(const int* __restrict__ src, const int* __restrict__ dst,
                            const float* __restrict__ norm, const float* __restrict__ B0,
                            float* __restrict__ acc1) {
    int t = blockIdx.x * blockDim.x + threadIdx.x;
    if (t >= NE * HID) return;
    int e = t >> 4;
    int f = t & 15;
    float v = norm[e] * B0[src[e] * HID + f];
    atomicAdd(&acc1[dst[e] * HID + f], v);
}

// h = relu(A1 + acc1 + b1), written back into A1
__global__ void k_h(float* __restrict__ A1, const float* __restrict__ acc1,
                    const float* __restrict__ b1) {
    int i = blockIdx.x * blockDim.x + threadIdx.x;
    if (i < NN * HID) {
        float v = A1[i] + acc1[i] + b1[i & 15];
        A1[i] = v > 0.f ? v : 0.f;
    }
}

// out[n][j] = sum_f h[n][f] * W2[0][f][j] + b2[j];  B1[n][j] = sum_f h[n][f]*W2[1][f][j]
__global__ void k_mm2(const float* __restrict__ h, const float* __restrict__ W2,
                      const float* __restrict__ b2,
                      float* __restrict__ out, float* __restrict__ B1) {
    __shared__ float w[2 * HID * NC];  // 1280 floats
    int tid = threadIdx.x;
    for (int i = tid; i < 2 * HID * NC; i += 320) w[i] = W2[i];
    __syncthreads();
    int node = blockIdx.x * 4 + tid / 80;
    int c = tid % 80;
    int sel = c / 40, jj = c - sel * 40;
    if (node >= NN) return;
    const float* hr = h + node * HID;
    const float* wp = w + sel * (HID * NC) + jj;
    float acc = 0.f;
    #pragma unroll
    for (int f = 0; f < HID; ++f) acc += hr[f] * wp[f * NC];
    if (sel == 0) out[node * NC + jj] = acc + b2[jj];
    else          B1[node * NC + jj] = acc;
}

// out[dst[e]][f] += norm[e] * B1[src[e]][f],  40 consecutive threads per edge
__global__ void k_scatter40(const int* __restrict__ src, const int* __restrict__ dst,
                            const float* __restrict__ norm, const float* __restrict__ B1,
                            float* __restrict__ out) {
    int t = blockIdx.x * blockDim.x + threadIdx.x;
    if (t >= NE * NC) return;
    int e = t / NC;
    int f = t - e * NC;
    float v = norm[e] * B1[src[e] * NC + f];
    atomicAdd(&out[dst[e] * NC + f], v);
}

// in-place log_softmax per row of 40, one wave64 per node
__global__ void k_lsm(float* __restrict__ out) {
    int node = blockIdx.x * 4 + (threadIdx.x >> 6);
    int lane = threadIdx.x & 63;
    if (node >= NN) return;
    float v = lane < NC ? out[node * NC + lane] : -INFINITY;
    float m = v;
    #pragma unroll
    for (int s = 32; s > 0; s >>= 1) m = fmaxf(m, __shfl_xor(m, s, 64));
    float ex = lane < NC ? expf(v - m) : 0.f;
    float sum = ex;
    #pragma unroll
    for (int s = 32; s > 0; s >>= 1) sum += __shfl_xor(sum, s, 64);
    if (lane < NC) out[node * NC + lane] = v - m - logf(sum);
}

extern "C" void kernel_launch(void* const* d_in, const int* in_sizes, int n_in,
                              void* d_out, int out_size, void* d_ws, size_t ws_size,
                              hipStream_t stream) {
    const float* x  = (const float*)d_in[0];
    const float* ew = (const float*)d_in[1];
    const float* W1 = (const float*)d_in[2];
    const float* b1 = (const float*)d_in[3];
    const float* W2 = (const float*)d_in[4];
    const float* b2 = (const float*)d_in[5];
    const int*   ei = (const int*)d_in[6];
    const int* src = ei;
    const int* dst = ei + NE;
    float* out = (float*)d_out;

    float* ws   = (float*)d_ws;
    float* deg  = ws;                    // N (padded to 100352)
    float* norm = deg + 100352;          // E
    float* A1   = norm + NE;             // N*16
    float* B0   = A1 + NN * HID;         // N*16
    float* acc1 = B0 + NN * HID;         // N*16
    float* B1   = acc1 + NN * HID;       // N*40
    // total ~10.5M floats ~ 42 MB

    hipMemsetAsync(deg, 0, NN * sizeof(float), stream);
    hipMemsetAsync(acc1, 0, (size_t)NN * HID * sizeof(float), stream);

    k_deg<<<(NE + 255) / 256, 256, 0, stream>>>(dst, ew, deg);
    k_dinv<<<(NN + 255) / 256, 256, 0, stream>>>(deg);
    k_norm<<<(NE + 255) / 256, 256, 0, stream>>>(src, dst, ew, deg, norm);
    k_mm1<<<(NN + 7) / 8, 256, 0, stream>>>(x, W1, A1, B0);
    k_scatter16<<<(NE * HID + 255) / 256, 256, 0, stream>>>(src, dst, norm, B0, acc1);
    k_h<<<(NN * HID + 255) / 256, 256, 0, stream>>>(A1, acc1, b1);
    k_mm2<<<(NN + 3) / 4, 320, 0, stream>>>(A1, W2, b2, out, B1);
    k_scatter40<<<(NE * NC + 255) / 256, 256, 0, stream>>>(src, dst, norm, B1, out);
    k_lsm<<<(NN + 3) / 4, 256, 0, stream>>>(out);
}